// Round 8
// baseline (277.544 us; speedup 1.0000x reference)
//
#include <hip/hip_runtime.h>
#include <hip/hip_bf16.h>
#include <cstdint>

typedef unsigned short u16;
typedef __bf16 bf16x8 __attribute__((ext_vector_type(8)));
typedef float floatx4 __attribute__((ext_vector_type(4)));

#define AS1 __attribute__((address_space(1)))
#define AS3 __attribute__((address_space(3)))

// round-to-nearest-even f32 -> bf16 bits
static __device__ __forceinline__ u16 f2bf(float f) {
    union { float f; unsigned int u; } v; v.f = f;
    unsigned int u = v.u;
    return (u16)((u + 0x7FFFu + ((u >> 16) & 1u)) >> 16);
}

// ---------------------------------------------------------------------------
// Transpose + fp32->bf16: in[R][Ccols] -> out[Ccols][R]
// ---------------------------------------------------------------------------
__device__ __forceinline__ void transpose_body(
    const float* __restrict__ in, u16* __restrict__ out,
    int R, int Ccols, int bx, int by, int tid, float (*tile)[33])
{
    const int tx = tid & 31;
    const int ty = tid >> 5;    // 0..7
    const int c0 = bx * 32;
    const int r0 = by * 32;
#pragma unroll
    for (int i = 0; i < 32; i += 8)
        tile[ty + i][tx] = in[(size_t)(r0 + ty + i) * Ccols + (c0 + tx)];
    __syncthreads();
#pragma unroll
    for (int i = 0; i < 32; i += 8)
        out[(size_t)(c0 + ty + i) * R + (r0 + tx)] = f2bf(tile[tx][ty + i]);
}

// ---------------------------------------------------------------------------
// Prep: [0,4096) transpose+cvt w1 (1024x4096 -> W1t[4096][1024]);
//       [4096,12288) LayerNorm rows -> X bf16.
// (w2 transpose rides inside GEMM1's grid, soaking its idle cycles.)
// ---------------------------------------------------------------------------
__global__ __launch_bounds__(256)
void prep(const float* __restrict__ w1, const float* __restrict__ act,
          const float* __restrict__ ln_scale, const float* __restrict__ ln_bias,
          u16* __restrict__ W1t, u16* __restrict__ X)
{
    __shared__ float smem[32][33];
    const int id  = blockIdx.x;
    const int tid = threadIdx.x;

    if (id < 4096) {
        transpose_body(w1, W1t, 1024, 4096, id & 127, id >> 7, tid, smem);
        return;
    }
    const int row = id - 4096;
    const float4 v = ((const float4*)(act + (size_t)row * 1024))[tid];
    float s  = v.x + v.y + v.z + v.w;
    float ss = v.x * v.x + v.y * v.y + v.z * v.z + v.w * v.w;
#pragma unroll
    for (int off = 32; off > 0; off >>= 1) {
        s  += __shfl_xor(s, off, 64);
        ss += __shfl_xor(ss, off, 64);
    }
    float* red = &smem[0][0];
    const int wave = tid >> 6, lane = tid & 63;
    if (lane == 0) { red[wave] = s; red[4 + wave] = ss; }
    __syncthreads();
    s  = red[0] + red[1] + red[2] + red[3];
    ss = red[4] + red[5] + red[6] + red[7];
    const float mu  = s * (1.0f / 1024.0f);
    const float var = ss * (1.0f / 1024.0f) - mu * mu;
    const float rs  = rsqrtf(var + 1e-5f);
    const float4 sc = ((const float4*)ln_scale)[tid];
    const float4 bi = ((const float4*)ln_bias)[tid];
    ushort4 o;
    o.x = f2bf((v.x - mu) * rs * sc.x + bi.x);
    o.y = f2bf((v.y - mu) * rs * sc.y + bi.y);
    o.z = f2bf((v.z - mu) * rs * sc.z + bi.z);
    o.w = f2bf((v.w - mu) * rs * sc.w + bi.w);
    ((ushort4*)(X + (size_t)row * 1024))[tid] = o;
}

// ---------------------------------------------------------------------------
// bf16 GEMM: C[M][N] = A[M][K] * Bt[N][K]^T + bias (+ReLU)
// 128x128 tile, templated BK, 4 waves 2x2, 4x4 16x16x32 MFMA per wave.
// XOR bank swizzle (R2: conflicts -> 0). Operand-swapped MFMA -> contiguous
// epilogue stores. bm-fastest block order (R5/R6 regressions reverted).
//
// R8 PIPELINE: loads for tile k+1 are issued AFTER all waves finish reading
// tile k (mid barrier) and BEFORE the last half's MFMAs, so the compiler's
// mandatory vmcnt(0)-before-barrier drain at loop bottom lands ~16 MFMAs
// (~1200 CU-cyc at 16 waves/CU) after issue -> staging latency hidden inside
// a single-buffer 2-barrier structure. (Double-buffer variants are defeated
// by the same vmcnt(0) — m99/m100/m131-141.)
//
// TRANS: trailing grid blocks run the w2 transpose (mem-only, soak idle).
// ---------------------------------------------------------------------------
template <int BK, bool BF16_OUT, bool RELU, bool TRANS>
__global__ __launch_bounds__(256)
void gemm_bt(const u16* __restrict__ A,      // [M][K] bf16 bits
             const u16* __restrict__ Bt,     // [N][K] bf16 bits
             const float* __restrict__ bias, // [N]
             void* __restrict__ Cout,
             int M, int N, int K,
             const float* __restrict__ tin,  // TRANS: src fp32 [TR][TC]
             u16* __restrict__ tout,         // TRANS: dst bf16 [TC][TR]
             int TR, int TC)
{
    constexpr int SLOTS  = BK / 8;      // 16B slots per LDS row (8/16)
    constexpr int RPI    = 64 / SLOTS;  // rows per 1KB wave issue
    constexpr int IPW    = SLOTS / 2;   // issues per wave per matrix
    constexpr int HALVES = BK / 32;     // k-halves per LDS tile

    const int nbm = M >> 7;
    const int nbn = N >> 7;
    const int id  = blockIdx.x;

    if constexpr (TRANS) {
        if (id >= nbm * nbn) {
            __shared__ float tile[32][33];
            const int t   = id - nbm * nbn;
            const int nbx = TC / 32;
            transpose_body(tin, tout, TR, TC, t % nbx, t / nbx,
                           threadIdx.x, tile);
            return;
        }
    }

    __shared__ __align__(16) u16 Alds[128 * BK];
    __shared__ __align__(16) u16 Blds[128 * BK];

    const int tid  = threadIdx.x;
    const int wave = tid >> 6;
    const int lane = tid & 63;
    const int wm   = wave & 1;
    const int wn   = wave >> 1;
    const int quad = lane >> 4;
    const int l16  = lane & 15;

    const int bm  = id % nbm;
    const int bn  = id / nbm;

    const u16* Ag = A  + (size_t)bm * 128 * K;
    const u16* Bg = Bt + (size_t)bn * 128 * K;

    const int srow = lane / SLOTS;
    const int s_st = lane & (SLOTS - 1);
    const int rkey = (SLOTS == 4) ? ((l16 >> 1) & 3) : (l16 & (SLOTS - 1));

    auto stage = [&](int k0) {
#pragma unroll
        for (int r = 0; r < IPW; ++r) {
            const int chunk = wave * IPW + r;
            const int row = chunk * RPI + srow;
            const int key = (SLOTS == 4) ? ((row >> 1) & 3)
                                         : (row & (SLOTS - 1));
            const int scol = (s_st ^ key) * 8;
            __builtin_amdgcn_global_load_lds(
                (AS1 void*)(Ag + (size_t)row * K + k0 + scol),
                (AS3 void*)(&Alds[chunk * 512]), 16, 0, 0);
            __builtin_amdgcn_global_load_lds(
                (AS1 void*)(Bg + (size_t)row * K + k0 + scol),
                (AS3 void*)(&Blds[chunk * 512]), 16, 0, 0);
        }
    };

    floatx4 acc[4][4];
#pragma unroll
    for (int i = 0; i < 4; ++i)
#pragma unroll
        for (int j = 0; j < 4; ++j)
            acc[i][j] = (floatx4){0.f, 0.f, 0.f, 0.f};

    stage(0);
    __syncthreads();   // tile 0 landed

    for (int k0 = 0; k0 < K; k0 += BK) {
        // halves 0..H-2: read frags, MFMA immediately
#pragma unroll
        for (int h = 0; h < HALVES - 1; ++h) {
            const int slot = ((quad + 4 * h) ^ rkey) * 8;
            bf16x8 bfr[4];
#pragma unroll
            for (int ni = 0; ni < 4; ++ni) {
                const int brow = wn * 64 + ni * 16 + l16;
                bfr[ni] = *(const bf16x8*)(&Blds[brow * BK + slot]);
            }
#pragma unroll
            for (int mi = 0; mi < 4; ++mi) {
                const int arow = wm * 64 + mi * 16 + l16;
                const bf16x8 a = *(const bf16x8*)(&Alds[arow * BK + slot]);
#pragma unroll
                for (int ni = 0; ni < 4; ++ni)
                    acc[mi][ni] = __builtin_amdgcn_mfma_f32_16x16x32_bf16(
                        bfr[ni], a, acc[mi][ni], 0, 0, 0);
            }
        }
        // last half: read frags into regs only
        const int slotL = ((quad + 4 * (HALVES - 1)) ^ rkey) * 8;
        bf16x8 aL[4], bL[4];
#pragma unroll
        for (int mi = 0; mi < 4; ++mi) {
            const int arow = wm * 64 + mi * 16 + l16;
            aL[mi] = *(const bf16x8*)(&Alds[arow * BK + slotL]);
        }
#pragma unroll
        for (int ni = 0; ni < 4; ++ni) {
            const int brow = wn * 64 + ni * 16 + l16;
            bL[ni] = *(const bf16x8*)(&Blds[brow * BK + slotL]);
        }
        __syncthreads();            // all waves done reading tile k (vmcnt already 0)
        if (k0 + BK < K) stage(k0 + BK);   // overwrite LDS with tile k+1
        // last half MFMAs — the hiding window for the staging latency
#pragma unroll
        for (int mi = 0; mi < 4; ++mi)
#pragma unroll
            for (int ni = 0; ni < 4; ++ni)
                acc[mi][ni] = __builtin_amdgcn_mfma_f32_16x16x32_bf16(
                    bL[ni], aL[mi], acc[mi][ni], 0, 0, 0);
        __syncthreads();            // compiler vmcnt(0): tile k+1 landed
    }

    // epilogue: lane (l16, quad) of acc[mi][ni] holds
    //   C[m = mbase+mi*16+l16][n = nbase+ni*16+quad*4 + r], r contiguous
    const int mbase = bm * 128 + wm * 64;
    const int nbase = bn * 128 + wn * 64;
#pragma unroll
    for (int mi = 0; mi < 4; ++mi) {
        const int m = mbase + mi * 16 + l16;
#pragma unroll
        for (int ni = 0; ni < 4; ++ni) {
            const int n0 = nbase + ni * 16 + quad * 4;
            const float4 bv = *(const float4*)&bias[n0];
            float v0 = acc[mi][ni][0] + bv.x;
            float v1 = acc[mi][ni][1] + bv.y;
            float v2 = acc[mi][ni][2] + bv.z;
            float v3 = acc[mi][ni][3] + bv.w;
            if (RELU) {
                v0 = fmaxf(v0, 0.f); v1 = fmaxf(v1, 0.f);
                v2 = fmaxf(v2, 0.f); v3 = fmaxf(v3, 0.f);
            }
            if (BF16_OUT) {
                ushort4 o = { f2bf(v0), f2bf(v1), f2bf(v2), f2bf(v3) };
                *(ushort4*)&((u16*)Cout)[(size_t)m * N + n0] = o;
            } else {
                float4 o = { v0, v1, v2, v3 };
                *(float4*)&((float*)Cout)[(size_t)m * N + n0] = o;
            }
        }
    }
}

// ---------------------------------------------------------------------------
// inputs: 0 act(4,2048,1024) f32, 1 mask(unused), 2 ln_scale(1024),
//         3 ln_bias(1024), 4 w1(1024,4096), 5 b1(4096), 6 w2(4096,1024),
//         7 b2(1024). out: (4,2048,1024) f32.
// ws layout (bf16 bits): X[8192*1024] | W1t[4096*1024] | W2t[1024*4096] |
//                        H[8192*4096]  -> 100,663,296 bytes total
// ---------------------------------------------------------------------------
extern "C" void kernel_launch(void* const* d_in, const int* in_sizes, int n_in,
                              void* d_out, int out_size, void* d_ws, size_t ws_size,
                              hipStream_t stream)
{
    const float* act      = (const float*)d_in[0];
    const float* ln_scale = (const float*)d_in[2];
    const float* ln_bias  = (const float*)d_in[3];
    const float* w1       = (const float*)d_in[4];
    const float* b1       = (const float*)d_in[5];
    const float* w2       = (const float*)d_in[6];
    const float* b2       = (const float*)d_in[7];
    float* out = (float*)d_out;

    const int M = 8192, C = 1024, CI = 4096;

    u16* X   = (u16*)d_ws;                 // [M][C]
    u16* W1t = X   + (size_t)M * C;        // [CI][C]
    u16* W2t = W1t + (size_t)CI * C;       // [C][CI]
    u16* H   = W2t + (size_t)C * CI;       // [M][CI]

    // prep: w1 transpose + layernorm (w2 transpose rides in GEMM1)
    prep<<<12288, 256, 0, stream>>>(w1, act, ln_scale, ln_bias, W1t, X);
    // H = relu(X @ W1 + b1), bf16; trailing 4096 blocks transpose w2 -> W2t
    gemm_bt<64, true, true, true>
        <<<(M / 128) * (CI / 128) + 4096, 256, 0, stream>>>(
        X, W1t, b1, (void*)H, M, CI, C, w2, W2t, 4096, 1024);
    // out = H @ W2 + b2, fp32, BK=128 (grid-limited -> 64KB LDS free)
    gemm_bt<128, false, false, false>
        <<<(M / 128) * (C / 128), 256, 0, stream>>>(
        H, W2t, b2, (void*)out, M, C, CI, nullptr, nullptr, 0, 0);
}